// Round 10
// baseline (3210.482 us; speedup 1.0000x reference)
//
#include <hip/hip_runtime.h>
#include <stdint.h>
#include <stddef.h>

#define VOCAB 41
#define EMB   512
#define HID   1024
#define H3    3072
#define BB    128
#define TT    256
#define BT    (BB*TT)
#define NSLOT 8
#define SLOT_U64 32768        // 256 KB per slot

typedef unsigned short u16;
typedef _Float16 half_t;
typedef half_t f16x8 __attribute__((ext_vector_type(8)));
typedef float f32x4 __attribute__((ext_vector_type(4)));
typedef unsigned long long u64;
typedef u64 u64x2 __attribute__((ext_vector_type(2)));

__device__ __forceinline__ float bf2f(u16 u) {
  return __uint_as_float(((uint32_t)u) << 16);
}
__device__ __forceinline__ u16 f2bf(float f) {
  uint32_t x = __float_as_uint(f);
  return (u16)((x + 0x7FFFu + ((x >> 16) & 1u)) >> 16);
}
__device__ __forceinline__ u16 f2h_bits(float f) {
  half_t h = (half_t)f;
  return __builtin_bit_cast(u16, h);
}
__device__ __forceinline__ float sigmoidf_(float x) {
  return 1.0f / (1.0f + __expf(-x));
}
__device__ __forceinline__ float tanh_fast(float x) {
  return 1.0f - 2.0f / (__expf(2.0f * x) + 1.0f);
}
__device__ __forceinline__ u64 aload64(const u64* p) {
  return __hip_atomic_load(p, __ATOMIC_RELAXED, __HIP_MEMORY_SCOPE_AGENT);
}
__device__ __forceinline__ void astore64(u64* p, u64 v) {
  __hip_atomic_store(p, v, __ATOMIC_RELAXED, __HIP_MEMORY_SCOPE_AGENT);
}
__device__ __forceinline__ void astore32(int* p, int v) {
  __hip_atomic_store(p, v, __ATOMIC_RELAXED, __HIP_MEMORY_SCOPE_AGENT);
}
// Cheap pre-filter: 64 packed flag words (256 B), lane i watches producer i.
__device__ __forceinline__ void poll_flags_packed(const int* flg, int lane,
                                                  int target) {
  int cap = 0;
  while (true) {
    int v = __hip_atomic_load(flg + lane, __ATOMIC_RELAXED,
                              __HIP_MEMORY_SCOPE_AGENT);
    if (__ballot(v < target) == 0ULL) break;
    __builtin_amdgcn_s_sleep(1);
    if (++cap > (1 << 16)) break;   // hint only -- tags below are the truth
  }
}

// ---------- prologue kernels (r9-identical) ----------

__global__ void detect_kernel(const u16* __restrict__ raw, int* __restrict__ flag) {
  __shared__ int s[256];
  int tid = threadIdx.x, cnt = 0;
  for (int i = tid; i < 4096; i += 256) {
    int e = (raw[i] >> 7) & 0xFF;
    if (e >= 132) cnt++;
  }
  s[tid] = cnt; __syncthreads();
  if (tid == 0) {
    int tot = 0;
    for (int i = 0; i < 256; i++) tot += s[i];
    *flag = (tot > 4) ? 1 : 0;
  }
}

__global__ void conv_kernel(const void* __restrict__ src, float* __restrict__ dst,
                            int n, const int* __restrict__ flag) {
  int i = blockIdx.x * 256 + threadIdx.x;
  if (i >= n) return;
  if (*flag) dst[i] = ((const float*)src)[i];
  else       dst[i] = bf2f(((const u16*)src)[i]);
}

__global__ void tokm_kernel(const int* __restrict__ x,
                            const unsigned char* __restrict__ m,
                            int* __restrict__ tokm) {
  int i = blockIdx.x * 256 + threadIdx.x;
  unsigned char b0 = m[0], b1 = m[1];
  bool t;
  if (b0 == 1) {
    if (b1 != 0) t = (m[i] != 0);
    else         t = (((const int*)m)[i] != 0);
  } else if (b0 == 0x80) {
    t = (((const u16*)m)[i] != 0);
  } else {
    t = (((const float*)m)[i] != 0.0f);
  }
  tokm[i] = x[i] | (t ? 0 : 0x80000000);
}

__global__ __launch_bounds__(256) void proj_kernel(
    const void* __restrict__ emb, const void* __restrict__ gk,
    const float* __restrict__ gbf, float* __restrict__ P,
    const int* __restrict__ flag) {
  int v = blockIdx.x / (H3 / 256);
  int j = (blockIdx.x % (H3 / 256)) * 256 + threadIdx.x;
  float acc = gbf[j];
  if (*flag) {
    const float* e = (const float*)emb + v * EMB;
    const float* g = (const float*)gk;
    for (int k = 0; k < EMB; ++k) acc = fmaf(e[k], g[k * H3 + j], acc);
  } else {
    const u16* e = (const u16*)emb + v * EMB;
    const u16* g = (const u16*)gk;
    for (int k = 0; k < EMB; ++k) acc = fmaf(bf2f(e[k]), bf2f(g[k * H3 + j]), acc);
  }
  P[v * H3 + j] = acc;
}

__global__ void p2_kernel(const float* __restrict__ P, const float* __restrict__ gbf,
                          float* __restrict__ P2) {
  int gc = blockIdx.x;
  int v = threadIdx.x;
  if (v >= VOCAB) return;
  float val = P[v * H3 + gc];
  if (gc < 2048) val += gbf[H3 + gc];
  P2[gc * VOCAB + v] = val;
}

__global__ void pack_wimg_kernel(const void* __restrict__ src, u16* __restrict__ img,
                                 const int* __restrict__ flag) {
  int idx = blockIdx.x * 256 + threadIdx.x;
  int j = idx & 7;
  int t1 = idx >> 3;
  int lane = t1 & 63;
  int t2 = t1 >> 6;
  int g = t2 % 3;
  int t3 = t2 / 3;
  int ks = t3 & 31;
  int ds = t3 >> 5;
  int k = ks * 32 + (lane >> 4) * 8 + j;
  int col = g * 1024 + ds * 16 + (lane & 15);
  float val;
  if (*flag) val = ((const float*)src)[(size_t)k * H3 + col];
  else       val = bf2f(((const u16*)src)[(size_t)k * H3 + col]);
  img[idx] = f2h_bits(val);
}

__global__ void pack_dimg_kernel(const void* __restrict__ src, u16* __restrict__ img,
                                 const int* __restrict__ flag) {
  int idx = blockIdx.x * 256 + threadIdx.x;
  int j = idx & 7;
  int t1 = idx >> 3;
  int lane = t1 & 63;
  int t2 = t1 >> 6;
  int ct = t2 % 3;
  int ks = t2 / 3;
  int k = ks * 32 + (lane >> 4) * 8 + j;
  int v = ct * 16 + (lane & 15);
  float val = 0.0f;
  if (v < VOCAB) {
    if (*flag) val = ((const float*)src)[(size_t)k * VOCAB + v];
    else       val = bf2f(((const u16*)src)[(size_t)k * VOCAB + v]);
  }
  img[idx] = f2h_bits(val);
}

// ---------- persistent GRU: flag pre-filter + tag-verified exchange ------
// 512 blocks x 256 thr (2/CU). bid = ds*8 + gt. Block: 16 rows (gt) x
// 16 dims (ds), K split across 4 waves; W frags persistent in regs.
// Producer: tagged data stores (LSB = generation parity) + ONE plain flag
// store -- no drain, no RMW. Consumer: cheap 256B flag poll (hint), then
// data load with tag verification (truth). Flags wrong-ordered => tag loop
// retries; flags lost => tag loop alone completes the handshake.
__global__ __launch_bounds__(256, 2) void gru_persist(
    const uint4* __restrict__ Wimg, const int* __restrict__ tokm,
    const float* __restrict__ P2, const float* __restrict__ gbf,
    u64* __restrict__ exch, u16* __restrict__ Hout,
    int* __restrict__ flags) {
  int bid = blockIdx.x;
  int gt = bid & 7, ds = bid >> 3;
  int tid = threadIdx.x;
  int w = tid >> 6, lane = tid & 63;

  __shared__ float red[4][64][13];
  __shared__ u16 tr[256];
  __shared__ float Pl[3][16][49];
  __shared__ int tokL[16 * 259];       // stride 259: conflict-free token reads

  // persistent B fragments: 3 gates x 8 k-steps (this wave's K-quarter)
  f16x8 breg[3][8];
  {
    const uint4* wsrc = Wimg + (size_t)ds * 96 * 64 + lane;
    #pragma unroll
    for (int k8 = 0; k8 < 8; ++k8)
      #pragma unroll
      for (int g = 0; g < 3; ++g)
        breg[g][k8] = __builtin_bit_cast(f16x8, wsrc[((w * 8 + k8) * 3 + g) * 64]);
  }

  // preload epilogue tables: P2 slice (3x16x41) and token map (16x256)
  for (int i = tid; i < 3 * 16 * VOCAB; i += 256) {
    int v = i % VOCAB;
    int t1 = i / VOCAB;
    int di = t1 & 15, g = t1 >> 4;
    Pl[g][di][v] = P2[(size_t)(g * 1024 + ds * 16 + di) * VOCAB + v];
  }
  for (int i = tid; i < 16 * 256; i += 256) {
    int rr = i >> 8, cc = i & 255;
    tokL[rr * 259 + cc] = tokm[gt * 4096 + i];
  }

  // per-thread epilogue ownership: one (row, dim) pair
  int row = tid >> 4, dim = tid & 15;
  int lane_src = (row >> 2) * 16 + dim;
  int rg = row & 3;
  float b1h = gbf[H3 + 2048 + ds * 16 + dim];
  float hcur = 0.f;
  int ks_blk = ds >> 1, q0 = (ds & 1) * 2;
  const int* flg = flags + gt * 64;
  __syncthreads();

  for (int t = 0; t < TT; ++t) {
    u64 av[16];
    {
      u64 etag = (u64)((t >> 3) & 1);
      const u64* abase = exch + (size_t)(t & 7) * SLOT_U64 + gt * 4096 +
                         (w * 8) * 128 + lane * 2;
      if (t > 0) poll_flags_packed(flg, lane, t);     // cheap hint
      int cap = 0;
      while (true) {                                   // tag-verified truth
        #pragma unroll
        for (int i = 0; i < 8; ++i) {
          av[2 * i]     = aload64(abase + i * 128);
          av[2 * i + 1] = aload64(abase + i * 128 + 1);
        }
        u64 bad = 0;
        #pragma unroll
        for (int i = 0; i < 16; ++i) bad |= (av[i] ^ etag) & 1ULL;
        if (__ballot(bad != 0ULL) == 0ULL) break;
        __builtin_amdgcn_s_sleep(2);
        if (++cap > (1 << 14)) break;   // fail fast instead of hanging
      }
    }

    f32x4 acc0 = {0.f, 0.f, 0.f, 0.f};
    f32x4 acc1 = {0.f, 0.f, 0.f, 0.f};
    f32x4 acc2 = {0.f, 0.f, 0.f, 0.f};
    #pragma unroll
    for (int k8 = 0; k8 < 8; ++k8) {
      u64x2 pair; pair.x = av[2 * k8]; pair.y = av[2 * k8 + 1];
      f16x8 a = __builtin_bit_cast(f16x8, pair);
      acc0 = __builtin_amdgcn_mfma_f32_16x16x32_f16(a, breg[0][k8], acc0, 0, 0, 0);
      acc1 = __builtin_amdgcn_mfma_f32_16x16x32_f16(a, breg[1][k8], acc1, 0, 0, 0);
      acc2 = __builtin_amdgcn_mfma_f32_16x16x32_f16(a, breg[2][k8], acc2, 0, 0, 0);
    }

    {
      float* q = red[w][lane];
      q[0] = acc0[0]; q[1] = acc0[1]; q[2]  = acc0[2]; q[3]  = acc0[3];
      q[4] = acc1[0]; q[5] = acc1[1]; q[6]  = acc1[2]; q[7]  = acc1[3];
      q[8] = acc2[0]; q[9] = acc2[1]; q[10] = acc2[2]; q[11] = acc2[3];
    }
    __syncthreads();                                   // S2

    // per-thread reduce over 4 K-quarters + gate epilogue
    {
      float a0 = 0.f, a1 = 0.f, a2 = 0.f;
      #pragma unroll
      for (int ww = 0; ww < 4; ++ww) {
        const float* q = red[ww][lane_src];
        a0 += q[rg]; a1 += q[4 + rg]; a2 += q[8 + rg];
      }
      int tm = tokL[row * 259 + t];
      int tok = tm & 0xFFFF;
      float z  = sigmoidf_(Pl[0][dim][tok] + a0);
      float r_ = sigmoidf_(Pl[1][dim][tok] + a1);
      float hh = tanh_fast(Pl[2][dim][tok] + r_ * (a2 + b1h));
      if (tm >= 0) hcur = z * hcur + (1.0f - z) * hh;
      tr[(dim >> 3) * 128 + row * 8 + (dim & 7)] = f2h_bits(hcur);
    }
    __syncthreads();                                   // S3

    if (w == 0) {
      u64 ntag = (u64)(((t + 1) >> 3) & 1);
      u64 v = ((const u64*)tr)[lane];
      v = (v & ~1ULL) | ntag;                          // embed generation tag
      astore64(exch + (size_t)((t + 1) & 7) * SLOT_U64 + gt * 4096 +
                   ks_blk * 128 + q0 * 32 + lane, v);
      if (lane == 0)
        astore32(flags + gt * 64 + ds, t + 1);         // hint (no drain)
      // Hout store off the critical path (visible at kernel completion)
      if (lane < 32) {
        int qq = lane >> 4, mm = lane & 15;
        uint4 hv = ((const uint4*)tr)[lane];
        int b = gt * 16 + mm;
        size_t idx = ((size_t)(b * 16 + (t >> 4)) * 32 + ks_blk) * 64 +
                     (q0 + qq) * 16 + (t & 15);
        ((uint4*)Hout)[idx] = hv;
      }
    }
  }
}

// ---------- dense epilogue (r9-identical) ----------
__global__ __launch_bounds__(256) void dense_mfma(
    const u16* __restrict__ HoutImg, const uint4* __restrict__ dimg,
    const float* __restrict__ dbf, void* __restrict__ out,
    const int* __restrict__ flag) {
  __shared__ uint4 Bl[48 * 64];
  int tid = threadIdx.x;
  int w = tid >> 6, lane = tid & 63;
  int quad = lane >> 4, vi = lane & 15;
  int gt0 = blockIdx.x * 8 + w * 2;

  f32x4 acc[2][3];
  #pragma unroll
  for (int i = 0; i < 2; ++i)
    #pragma unroll
    for (int c = 0; c < 3; ++c) acc[i][c] = (f32x4){0.f, 0.f, 0.f, 0.f};

  for (int half = 0; half < 2; ++half) {
    for (int i = tid; i < 48 * 64; i += 256) Bl[i] = dimg[half * 48 * 64 + i];
    __syncthreads();
    #pragma unroll
    for (int ks16 = 0; ks16 < 16; ++ks16) {
      int ks = half * 16 + ks16;
      f16x8 a0 = __builtin_bit_cast(
          f16x8, ((const uint4*)HoutImg)[((size_t)gt0 * 32 + ks) * 64 + lane]);
      f16x8 a1 = __builtin_bit_cast(
          f16x8, ((const uint4*)HoutImg)[(((size_t)gt0 + 1) * 32 + ks) * 64 + lane]);
      #pragma unroll
      for (int c = 0; c < 3; ++c) {
        f16x8 bf = __builtin_bit_cast(f16x8, Bl[(ks16 * 3 + c) * 64 + lane]);
        acc[0][c] = __builtin_amdgcn_mfma_f32_16x16x32_f16(a0, bf, acc[0][c], 0, 0, 0);
        acc[1][c] = __builtin_amdgcn_mfma_f32_16x16x32_f16(a1, bf, acc[1][c], 0, 0, 0);
      }
    }
    __syncthreads();
  }

  int isf = *flag;
  #pragma unroll
  for (int i = 0; i < 2; ++i) {
    #pragma unroll
    for (int c = 0; c < 3; ++c) {
      int v = c * 16 + vi;
      if (v >= VOCAB) continue;
      float bias = dbf[v];
      #pragma unroll
      for (int rg = 0; rg < 4; ++rg) {
        size_t bt = (size_t)(gt0 + i) * 16 + quad * 4 + rg;
        float val = acc[i][c][rg] + bias;
        if (isf) ((float*)out)[bt * VOCAB + v] = val;
        else     ((u16*)out)[bt * VOCAB + v] = f2bf(val);
      }
    }
  }
}

// ---------- launch ----------

extern "C" void kernel_launch(void* const* d_in, const int* in_sizes, int n_in,
                              void* d_out, int out_size, void* d_ws, size_t ws_size,
                              hipStream_t stream) {
  const int* x            = (const int*)d_in[0];
  const unsigned char* mk = (const unsigned char*)d_in[1];

  char* ws = (char*)d_ws;
  int*   flag  = (int*)(ws + 0);
  float* dbf   = (float*)(ws + 4 * 1024);
  float* gbf   = (float*)(ws + 8 * 1024);            // 24 KB
  int*   flags = (int*)(ws + 40 * 1024);             // 8*64*4 = 2 KB packed
  int*   tokm  = (int*)(ws + 64 * 1024);             // 128 KB
  u16*   dimg  = (u16*)(ws + 192 * 1024);            // 96 KB
  float* P     = (float*)(ws + 288 * 1024);          // 504 KB
  float* P2    = (float*)(ws + 800 * 1024);          // 504 KB
  u64*   exch  = (u64*)(ws + 1312 * 1024);           // 2 MB (8 slots x 256 KB)
  u16*   Wimg  = (u16*)(ws + 3456 * 1024);           // 6 MB
  u16*   Hout  = (u16*)(ws + 10 * 1024 * 1024);      // 64 MB

  detect_kernel<<<1, 256, 0, stream>>>((const u16*)d_in[4], flag);
  conv_kernel<<<(2 * H3 + 255) / 256, 256, 0, stream>>>(d_in[5], gbf, 2 * H3, flag);
  conv_kernel<<<1, 256, 0, stream>>>(d_in[7], dbf, VOCAB, flag);
  tokm_kernel<<<BT / 256, 256, 0, stream>>>(x, mk, tokm);
  proj_kernel<<<VOCAB * (H3 / 256), 256, 0, stream>>>(d_in[2], d_in[3], gbf, P, flag);
  p2_kernel<<<H3, 64, 0, stream>>>(P, gbf, P2);
  pack_wimg_kernel<<<(64 * 32 * 3 * 64 * 8) / 256, 256, 0, stream>>>(d_in[4], Wimg, flag);
  pack_dimg_kernel<<<(32 * 3 * 64 * 8) / 256, 256, 0, stream>>>(d_in[6], dimg, flag);
  hipMemsetAsync(flags, 0, 2 * 1024, stream);
  // slot 0 = h_0 = zeros with tag 0 (valid for t=0).
  hipMemsetAsync(exch, 0, SLOT_U64 * 8, stream);
  // slots 1-7 = 0xFF: tag bit 1 = INVALID until first genuine write (their
  // first readers t=1..7 expect tag 0). Harness poison 0xAA has LSB 0 and
  // would be falsely accepted -- this memset is correctness-critical.
  hipMemsetAsync((char*)exch + SLOT_U64 * 8, 0xFF, 7 * SLOT_U64 * 8, stream);

  gru_persist<<<512, 256, 0, stream>>>((const uint4*)Wimg, tokm, P2, gbf,
                                       exch, Hout, flags);
  dense_mfma<<<256, 256, 0, stream>>>(Hout, (const uint4*)dimg, dbf, d_out, flag);
}

// Round 11
// 1578.019 us; speedup vs baseline: 2.0345x; 2.0345x over previous
//
#include <hip/hip_runtime.h>
#include <stdint.h>
#include <stddef.h>

#define VOCAB 41
#define EMB   512
#define HID   1024
#define H3    3072
#define BB    128
#define TT    256
#define BT    (BB*TT)
#define NSLOT 8
#define SLOT_U64 32768        // 256 KB per slot

typedef unsigned short u16;
typedef _Float16 half_t;
typedef half_t f16x8 __attribute__((ext_vector_type(8)));
typedef float f32x4 __attribute__((ext_vector_type(4)));
typedef unsigned long long u64;
typedef u64 u64x2 __attribute__((ext_vector_type(2)));

__device__ __forceinline__ float bf2f(u16 u) {
  return __uint_as_float(((uint32_t)u) << 16);
}
__device__ __forceinline__ u16 f2bf(float f) {
  uint32_t x = __float_as_uint(f);
  return (u16)((x + 0x7FFFu + ((x >> 16) & 1u)) >> 16);
}
__device__ __forceinline__ u16 f2h_bits(float f) {
  half_t h = (half_t)f;
  return __builtin_bit_cast(u16, h);
}
__device__ __forceinline__ float sigmoidf_(float x) {
  return 1.0f / (1.0f + __expf(-x));
}
__device__ __forceinline__ float tanh_fast(float x) {
  return 1.0f - 2.0f / (__expf(2.0f * x) + 1.0f);
}
__device__ __forceinline__ u64 aload64(const u64* p) {
  return __hip_atomic_load(p, __ATOMIC_RELAXED, __HIP_MEMORY_SCOPE_AGENT);
}
__device__ __forceinline__ void astore64(u64* p, u64 v) {
  __hip_atomic_store(p, v, __ATOMIC_RELAXED, __HIP_MEMORY_SCOPE_AGENT);
}
// Wave-parallel poll of 64 PACKED flag words (4 cache lines). Signal side
// uses atomicAdd RMW after a vmcnt(0) drain (r8 protocol, proven).
__device__ __forceinline__ void poll_flags(const int* flc, int lane, int target) {
  int cap = 0;
  while (true) {
    int v = __hip_atomic_load(flc + lane, __ATOMIC_RELAXED,
                              __HIP_MEMORY_SCOPE_AGENT);
    if (__ballot(v < target) == 0ULL) break;
    if (++cap > (1 << 17)) break;   // fail fast instead of hanging
  }
}

// ---------- prologue kernels (r8-identical) ----------

__global__ void detect_kernel(const u16* __restrict__ raw, int* __restrict__ flag) {
  __shared__ int s[256];
  int tid = threadIdx.x, cnt = 0;
  for (int i = tid; i < 4096; i += 256) {
    int e = (raw[i] >> 7) & 0xFF;
    if (e >= 132) cnt++;
  }
  s[tid] = cnt; __syncthreads();
  if (tid == 0) {
    int tot = 0;
    for (int i = 0; i < 256; i++) tot += s[i];
    *flag = (tot > 4) ? 1 : 0;
  }
}

__global__ void conv_kernel(const void* __restrict__ src, float* __restrict__ dst,
                            int n, const int* __restrict__ flag) {
  int i = blockIdx.x * 256 + threadIdx.x;
  if (i >= n) return;
  if (*flag) dst[i] = ((const float*)src)[i];
  else       dst[i] = bf2f(((const u16*)src)[i]);
}

__global__ void tokm_kernel(const int* __restrict__ x,
                            const unsigned char* __restrict__ m,
                            int* __restrict__ tokm) {
  int i = blockIdx.x * 256 + threadIdx.x;
  unsigned char b0 = m[0], b1 = m[1];
  bool t;
  if (b0 == 1) {
    if (b1 != 0) t = (m[i] != 0);
    else         t = (((const int*)m)[i] != 0);
  } else if (b0 == 0x80) {
    t = (((const u16*)m)[i] != 0);
  } else {
    t = (((const float*)m)[i] != 0.0f);
  }
  tokm[i] = x[i] | (t ? 0 : 0x80000000);
}

__global__ __launch_bounds__(256) void proj_kernel(
    const void* __restrict__ emb, const void* __restrict__ gk,
    const float* __restrict__ gbf, float* __restrict__ P,
    const int* __restrict__ flag) {
  int v = blockIdx.x / (H3 / 256);
  int j = (blockIdx.x % (H3 / 256)) * 256 + threadIdx.x;
  float acc = gbf[j];
  if (*flag) {
    const float* e = (const float*)emb + v * EMB;
    const float* g = (const float*)gk;
    for (int k = 0; k < EMB; ++k) acc = fmaf(e[k], g[k * H3 + j], acc);
  } else {
    const u16* e = (const u16*)emb + v * EMB;
    const u16* g = (const u16*)gk;
    for (int k = 0; k < EMB; ++k) acc = fmaf(bf2f(e[k]), bf2f(g[k * H3 + j]), acc);
  }
  P[v * H3 + j] = acc;
}

__global__ void p2_kernel(const float* __restrict__ P, const float* __restrict__ gbf,
                          float* __restrict__ P2) {
  int gc = blockIdx.x;
  int v = threadIdx.x;
  if (v >= VOCAB) return;
  float val = P[v * H3 + gc];
  if (gc < 2048) val += gbf[H3 + gc];
  P2[gc * VOCAB + v] = val;
}

__global__ void pack_wimg_kernel(const void* __restrict__ src, u16* __restrict__ img,
                                 const int* __restrict__ flag) {
  int idx = blockIdx.x * 256 + threadIdx.x;
  int j = idx & 7;
  int t1 = idx >> 3;
  int lane = t1 & 63;
  int t2 = t1 >> 6;
  int g = t2 % 3;
  int t3 = t2 / 3;
  int ks = t3 & 31;
  int ds = t3 >> 5;
  int k = ks * 32 + (lane >> 4) * 8 + j;
  int col = g * 1024 + ds * 16 + (lane & 15);
  float val;
  if (*flag) val = ((const float*)src)[(size_t)k * H3 + col];
  else       val = bf2f(((const u16*)src)[(size_t)k * H3 + col]);
  img[idx] = f2h_bits(val);
}

__global__ void pack_dimg_kernel(const void* __restrict__ src, u16* __restrict__ img,
                                 const int* __restrict__ flag) {
  int idx = blockIdx.x * 256 + threadIdx.x;
  int j = idx & 7;
  int t1 = idx >> 3;
  int lane = t1 & 63;
  int t2 = t1 >> 6;
  int ct = t2 % 3;
  int ks = t2 / 3;
  int k = ks * 32 + (lane >> 4) * 8 + j;
  int v = ct * 16 + (lane & 15);
  float val = 0.0f;
  if (v < VOCAB) {
    if (*flag) val = ((const float*)src)[(size_t)k * VOCAB + v];
    else       val = bf2f(((const u16*)src)[(size_t)k * VOCAB + v]);
  }
  img[idx] = f2h_bits(val);
}

// ---------- persistent GRU: r8 protocol, packed flags, tokL pad ----------
// 512 blocks x 256 thr (2/CU). bid = ds*8 + gt. Block: 16 rows (gt) x
// 16 dims (ds), K split across 4 waves; W frags persistent in regs.
// Producer: exch stores -> vmcnt(0) drain -> atomicAdd on own PACKED flag
// word. Consumer w0: wave-parallel poll of the 64 packed flags (4 lines).
__global__ __launch_bounds__(256, 2) void gru_persist(
    const uint4* __restrict__ Wimg, const int* __restrict__ tokm,
    const float* __restrict__ P2, const float* __restrict__ gbf,
    u64* __restrict__ exch, u16* __restrict__ Hout,
    int* __restrict__ flags) {
  int bid = blockIdx.x;
  int gt = bid & 7, ds = bid >> 3;
  int tid = threadIdx.x;
  int w = tid >> 6, lane = tid & 63;

  __shared__ float red[4][64][13];
  __shared__ u16 tr[256];
  __shared__ float Pl[3][16][49];
  __shared__ int tokL[16 * 259];       // stride 259: conflict-free token reads

  // persistent B fragments: 3 gates x 8 k-steps (this wave's K-quarter)
  f16x8 breg[3][8];
  {
    const uint4* wsrc = Wimg + (size_t)ds * 96 * 64 + lane;
    #pragma unroll
    for (int k8 = 0; k8 < 8; ++k8)
      #pragma unroll
      for (int g = 0; g < 3; ++g)
        breg[g][k8] = __builtin_bit_cast(f16x8, wsrc[((w * 8 + k8) * 3 + g) * 64]);
  }

  // preload epilogue tables: P2 slice (3x16x41) and token map (16x256)
  for (int i = tid; i < 3 * 16 * VOCAB; i += 256) {
    int v = i % VOCAB;
    int t1 = i / VOCAB;
    int di = t1 & 15, g = t1 >> 4;
    Pl[g][di][v] = P2[(size_t)(g * 1024 + ds * 16 + di) * VOCAB + v];
  }
  for (int i = tid; i < 16 * 256; i += 256) {
    int rr = i >> 8, cc = i & 255;
    tokL[rr * 259 + cc] = tokm[gt * 4096 + i];
  }

  // per-thread epilogue ownership: one (row, dim) pair
  int row = tid >> 4, dim = tid & 15;
  int lane_src = (row >> 2) * 16 + dim;
  int rg = row & 3;
  float b1h = gbf[H3 + 2048 + ds * 16 + dim];
  float hcur = 0.f;
  int ks_blk = ds >> 1, q0 = (ds & 1) * 2;
  int* flc = flags + gt * 64;          // 64 packed words = 4 cache lines

  for (int t = 0; t < TT; ++t) {
    if (t > 0 && w == 0) poll_flags(flc, lane, t);
    __syncthreads();                                   // S1

    // A loads: this wave's K-quarter of the 16-row tile, from slot t&7
    const u64* abase = exch + (size_t)(t & 7) * SLOT_U64 + gt * 4096 +
                       (w * 8) * 128 + lane * 2;
    u64 av[16];
    #pragma unroll
    for (int i = 0; i < 8; ++i) {
      av[2 * i]     = aload64(abase + i * 128);
      av[2 * i + 1] = aload64(abase + i * 128 + 1);
    }
    f32x4 acc0 = {0.f, 0.f, 0.f, 0.f};
    f32x4 acc1 = {0.f, 0.f, 0.f, 0.f};
    f32x4 acc2 = {0.f, 0.f, 0.f, 0.f};
    #pragma unroll
    for (int k8 = 0; k8 < 8; ++k8) {
      u64x2 pair; pair.x = av[2 * k8]; pair.y = av[2 * k8 + 1];
      f16x8 a = __builtin_bit_cast(f16x8, pair);
      acc0 = __builtin_amdgcn_mfma_f32_16x16x32_f16(a, breg[0][k8], acc0, 0, 0, 0);
      acc1 = __builtin_amdgcn_mfma_f32_16x16x32_f16(a, breg[1][k8], acc1, 0, 0, 0);
      acc2 = __builtin_amdgcn_mfma_f32_16x16x32_f16(a, breg[2][k8], acc2, 0, 0, 0);
    }

    {
      float* q = red[w][lane];
      q[0] = acc0[0]; q[1] = acc0[1]; q[2]  = acc0[2]; q[3]  = acc0[3];
      q[4] = acc1[0]; q[5] = acc1[1]; q[6]  = acc1[2]; q[7]  = acc1[3];
      q[8] = acc2[0]; q[9] = acc2[1]; q[10] = acc2[2]; q[11] = acc2[3];
    }
    __syncthreads();                                   // S2

    // per-thread reduce over 4 K-quarters + gate epilogue
    {
      float a0 = 0.f, a1 = 0.f, a2 = 0.f;
      #pragma unroll
      for (int ww = 0; ww < 4; ++ww) {
        const float* q = red[ww][lane_src];
        a0 += q[rg]; a1 += q[4 + rg]; a2 += q[8 + rg];
      }
      int tm = tokL[row * 259 + t];
      int tok = tm & 0xFFFF;
      float z  = sigmoidf_(Pl[0][dim][tok] + a0);
      float r_ = sigmoidf_(Pl[1][dim][tok] + a1);
      float hh = tanh_fast(Pl[2][dim][tok] + r_ * (a2 + b1h));
      if (tm >= 0) hcur = z * hcur + (1.0f - z) * hh;
      tr[(dim >> 3) * 128 + row * 8 + (dim & 7)] = f2h_bits(hcur);
    }
    __syncthreads();                                   // S3

    if (w == 0) {
      u64 v = ((const u64*)tr)[lane];
      astore64(exch + (size_t)((t + 1) & 7) * SLOT_U64 + gt * 4096 +
                   ks_blk * 128 + q0 * 32 + lane, v);
      __atomic_signal_fence(__ATOMIC_SEQ_CST);
      __builtin_amdgcn_s_waitcnt(0);                   // exch at coherence pt
      __atomic_signal_fence(__ATOMIC_SEQ_CST);
      if (lane == 0)
        __hip_atomic_fetch_add(flc + ds, 1, __ATOMIC_RELAXED,
                               __HIP_MEMORY_SCOPE_AGENT);
      // Hout store off the critical path (visible at kernel completion)
      if (lane < 32) {
        int qq = lane >> 4, mm = lane & 15;
        uint4 hv = ((const uint4*)tr)[lane];
        int b = gt * 16 + mm;
        size_t idx = ((size_t)(b * 16 + (t >> 4)) * 32 + ks_blk) * 64 +
                     (q0 + qq) * 16 + (t & 15);
        ((uint4*)Hout)[idx] = hv;
      }
    }
  }
}

// ---------- dense epilogue (r8-identical) ----------
__global__ __launch_bounds__(256) void dense_mfma(
    const u16* __restrict__ HoutImg, const uint4* __restrict__ dimg,
    const float* __restrict__ dbf, void* __restrict__ out,
    const int* __restrict__ flag) {
  __shared__ uint4 Bl[48 * 64];
  int tid = threadIdx.x;
  int w = tid >> 6, lane = tid & 63;
  int quad = lane >> 4, vi = lane & 15;
  int gt0 = blockIdx.x * 8 + w * 2;

  f32x4 acc[2][3];
  #pragma unroll
  for (int i = 0; i < 2; ++i)
    #pragma unroll
    for (int c = 0; c < 3; ++c) acc[i][c] = (f32x4){0.f, 0.f, 0.f, 0.f};

  for (int half = 0; half < 2; ++half) {
    for (int i = tid; i < 48 * 64; i += 256) Bl[i] = dimg[half * 48 * 64 + i];
    __syncthreads();
    #pragma unroll
    for (int ks16 = 0; ks16 < 16; ++ks16) {
      int ks = half * 16 + ks16;
      f16x8 a0 = __builtin_bit_cast(
          f16x8, ((const uint4*)HoutImg)[((size_t)gt0 * 32 + ks) * 64 + lane]);
      f16x8 a1 = __builtin_bit_cast(
          f16x8, ((const uint4*)HoutImg)[(((size_t)gt0 + 1) * 32 + ks) * 64 + lane]);
      #pragma unroll
      for (int c = 0; c < 3; ++c) {
        f16x8 bf = __builtin_bit_cast(f16x8, Bl[(ks16 * 3 + c) * 64 + lane]);
        acc[0][c] = __builtin_amdgcn_mfma_f32_16x16x32_f16(a0, bf, acc[0][c], 0, 0, 0);
        acc[1][c] = __builtin_amdgcn_mfma_f32_16x16x32_f16(a1, bf, acc[1][c], 0, 0, 0);
      }
    }
    __syncthreads();
  }

  int isf = *flag;
  #pragma unroll
  for (int i = 0; i < 2; ++i) {
    #pragma unroll
    for (int c = 0; c < 3; ++c) {
      int v = c * 16 + vi;
      if (v >= VOCAB) continue;
      float bias = dbf[v];
      #pragma unroll
      for (int rg = 0; rg < 4; ++rg) {
        size_t bt = (size_t)(gt0 + i) * 16 + quad * 4 + rg;
        float val = acc[i][c][rg] + bias;
        if (isf) ((float*)out)[bt * VOCAB + v] = val;
        else     ((u16*)out)[bt * VOCAB + v] = f2bf(val);
      }
    }
  }
}

// ---------- launch ----------

extern "C" void kernel_launch(void* const* d_in, const int* in_sizes, int n_in,
                              void* d_out, int out_size, void* d_ws, size_t ws_size,
                              hipStream_t stream) {
  const int* x            = (const int*)d_in[0];
  const unsigned char* mk = (const unsigned char*)d_in[1];

  char* ws = (char*)d_ws;
  int*   flag  = (int*)(ws + 0);
  float* dbf   = (float*)(ws + 4 * 1024);
  float* gbf   = (float*)(ws + 8 * 1024);            // 24 KB
  int*   flags = (int*)(ws + 40 * 1024);             // 8*64*4 = 2 KB packed
  int*   tokm  = (int*)(ws + 64 * 1024);             // 128 KB
  u16*   dimg  = (u16*)(ws + 192 * 1024);            // 96 KB
  float* P     = (float*)(ws + 288 * 1024);          // 504 KB
  float* P2    = (float*)(ws + 800 * 1024);          // 504 KB
  u64*   exch  = (u64*)(ws + 1312 * 1024);           // 2 MB (8 slots x 256 KB)
  u16*   Wimg  = (u16*)(ws + 3456 * 1024);           // 6 MB
  u16*   Hout  = (u16*)(ws + 10 * 1024 * 1024);      // 64 MB

  detect_kernel<<<1, 256, 0, stream>>>((const u16*)d_in[4], flag);
  conv_kernel<<<(2 * H3 + 255) / 256, 256, 0, stream>>>(d_in[5], gbf, 2 * H3, flag);
  conv_kernel<<<1, 256, 0, stream>>>(d_in[7], dbf, VOCAB, flag);
  tokm_kernel<<<BT / 256, 256, 0, stream>>>(x, mk, tokm);
  proj_kernel<<<VOCAB * (H3 / 256), 256, 0, stream>>>(d_in[2], d_in[3], gbf, P, flag);
  p2_kernel<<<H3, 64, 0, stream>>>(P, gbf, P2);
  pack_wimg_kernel<<<(64 * 32 * 3 * 64 * 8) / 256, 256, 0, stream>>>(d_in[4], Wimg, flag);
  pack_dimg_kernel<<<(32 * 3 * 64 * 8) / 256, 256, 0, stream>>>(d_in[6], dimg, flag);
  hipMemsetAsync(flags, 0, 2 * 1024, stream);
  hipMemsetAsync(exch, 0, SLOT_U64 * 8, stream);     // slot 0 = h_0 = zeros

  gru_persist<<<512, 256, 0, stream>>>((const uint4*)Wimg, tokm, P2, gbf,
                                       exch, Hout, flags);
  dense_mfma<<<256, 256, 0, stream>>>(Hout, (const uint4*)dimg, dbf, d_out, flag);
}

// Round 12
// 1208.960 us; speedup vs baseline: 2.6556x; 1.3053x over previous
//
#include <hip/hip_runtime.h>
#include <stdint.h>
#include <stddef.h>

#define VOCAB 41
#define EMB   512
#define HID   1024
#define H3    3072
#define BB    128
#define TT    256
#define BT    (BB*TT)
#define NSLOT 8
#define SLOT_U64 32768        // 256 KB per slot

typedef unsigned short u16;
typedef _Float16 half_t;
typedef half_t f16x8 __attribute__((ext_vector_type(8)));
typedef float f32x4 __attribute__((ext_vector_type(4)));
typedef unsigned long long u64;
typedef u64 u64x2 __attribute__((ext_vector_type(2)));

__device__ __forceinline__ float bf2f(u16 u) {
  return __uint_as_float(((uint32_t)u) << 16);
}
__device__ __forceinline__ u16 f2bf(float f) {
  uint32_t x = __float_as_uint(f);
  return (u16)((x + 0x7FFFu + ((x >> 16) & 1u)) >> 16);
}
__device__ __forceinline__ u16 f2h_bits(float f) {
  half_t h = (half_t)f;
  return __builtin_bit_cast(u16, h);
}
__device__ __forceinline__ float sigmoidf_(float x) {
  return 1.0f / (1.0f + __expf(-x));
}
__device__ __forceinline__ float tanh_fast(float x) {
  return 1.0f - 2.0f / (__expf(2.0f * x) + 1.0f);
}
__device__ __forceinline__ u64 aload64(const u64* p) {
  return __hip_atomic_load(p, __ATOMIC_RELAXED, __HIP_MEMORY_SCOPE_AGENT);
}
__device__ __forceinline__ void astore64(u64* p, u64 v) {
  __hip_atomic_store(p, v, __ATOMIC_RELAXED, __HIP_MEMORY_SCOPE_AGENT);
}
// Wave-parallel: lane i watches producer i's flag (stride 16 ints = 64 B --
// padding keeps each producer's RMW on its own cache line; r11 proved that
// packing them serializes the RMWs and regresses 40%).
__device__ __forceinline__ void poll_flags(const int* flc, int lane, int target) {
  int cap = 0;
  while (true) {
    int v = __hip_atomic_load(flc + lane * 16, __ATOMIC_RELAXED,
                              __HIP_MEMORY_SCOPE_AGENT);
    if (__ballot(v < target) == 0ULL) break;
    __builtin_amdgcn_s_sleep(1);
    if (++cap > (1 << 16)) break;   // fail fast instead of hanging
  }
}

// ---------- prologue kernels (r8-identical) ----------

__global__ void detect_kernel(const u16* __restrict__ raw, int* __restrict__ flag) {
  __shared__ int s[256];
  int tid = threadIdx.x, cnt = 0;
  for (int i = tid; i < 4096; i += 256) {
    int e = (raw[i] >> 7) & 0xFF;
    if (e >= 132) cnt++;
  }
  s[tid] = cnt; __syncthreads();
  if (tid == 0) {
    int tot = 0;
    for (int i = 0; i < 256; i++) tot += s[i];
    *flag = (tot > 4) ? 1 : 0;
  }
}

__global__ void conv_kernel(const void* __restrict__ src, float* __restrict__ dst,
                            int n, const int* __restrict__ flag) {
  int i = blockIdx.x * 256 + threadIdx.x;
  if (i >= n) return;
  if (*flag) dst[i] = ((const float*)src)[i];
  else       dst[i] = bf2f(((const u16*)src)[i]);
}

__global__ void tokm_kernel(const int* __restrict__ x,
                            const unsigned char* __restrict__ m,
                            int* __restrict__ tokm) {
  int i = blockIdx.x * 256 + threadIdx.x;
  unsigned char b0 = m[0], b1 = m[1];
  bool t;
  if (b0 == 1) {
    if (b1 != 0) t = (m[i] != 0);
    else         t = (((const int*)m)[i] != 0);
  } else if (b0 == 0x80) {
    t = (((const u16*)m)[i] != 0);
  } else {
    t = (((const float*)m)[i] != 0.0f);
  }
  tokm[i] = x[i] | (t ? 0 : 0x80000000);
}

__global__ __launch_bounds__(256) void proj_kernel(
    const void* __restrict__ emb, const void* __restrict__ gk,
    const float* __restrict__ gbf, float* __restrict__ P,
    const int* __restrict__ flag) {
  int v = blockIdx.x / (H3 / 256);
  int j = (blockIdx.x % (H3 / 256)) * 256 + threadIdx.x;
  float acc = gbf[j];
  if (*flag) {
    const float* e = (const float*)emb + v * EMB;
    const float* g = (const float*)gk;
    for (int k = 0; k < EMB; ++k) acc = fmaf(e[k], g[k * H3 + j], acc);
  } else {
    const u16* e = (const u16*)emb + v * EMB;
    const u16* g = (const u16*)gk;
    for (int k = 0; k < EMB; ++k) acc = fmaf(bf2f(e[k]), bf2f(g[k * H3 + j]), acc);
  }
  P[v * H3 + j] = acc;
}

__global__ void p2_kernel(const float* __restrict__ P, const float* __restrict__ gbf,
                          float* __restrict__ P2) {
  int gc = blockIdx.x;
  int v = threadIdx.x;
  if (v >= VOCAB) return;
  float val = P[v * H3 + gc];
  if (gc < 2048) val += gbf[H3 + gc];
  P2[gc * VOCAB + v] = val;
}

__global__ void pack_wimg_kernel(const void* __restrict__ src, u16* __restrict__ img,
                                 const int* __restrict__ flag) {
  int idx = blockIdx.x * 256 + threadIdx.x;
  int j = idx & 7;
  int t1 = idx >> 3;
  int lane = t1 & 63;
  int t2 = t1 >> 6;
  int g = t2 % 3;
  int t3 = t2 / 3;
  int ks = t3 & 31;
  int ds = t3 >> 5;
  int k = ks * 32 + (lane >> 4) * 8 + j;
  int col = g * 1024 + ds * 16 + (lane & 15);
  float val;
  if (*flag) val = ((const float*)src)[(size_t)k * H3 + col];
  else       val = bf2f(((const u16*)src)[(size_t)k * H3 + col]);
  img[idx] = f2h_bits(val);
}

__global__ void pack_dimg_kernel(const void* __restrict__ src, u16* __restrict__ img,
                                 const int* __restrict__ flag) {
  int idx = blockIdx.x * 256 + threadIdx.x;
  int j = idx & 7;
  int t1 = idx >> 3;
  int lane = t1 & 63;
  int t2 = t1 >> 6;
  int ct = t2 % 3;
  int ks = t2 / 3;
  int k = ks * 32 + (lane >> 4) * 8 + j;
  int v = ct * 16 + (lane & 15);
  float val = 0.0f;
  if (v < VOCAB) {
    if (*flag) val = ((const float*)src)[(size_t)k * VOCAB + v];
    else       val = bf2f(((const u16*)src)[(size_t)k * VOCAB + v]);
  }
  img[idx] = f2h_bits(val);
}

// ---------- persistent GRU: r8 protocol (proven best) + tokL pad ----------
// 512 blocks x 256 thr (2/CU). bid = ds*8 + gt. Block: 16 rows (gt) x
// 16 dims (ds), K split across 4 waves; W frags persistent in regs.
// Producer: exch stores -> vmcnt(0) drain -> atomicAdd on own PADDED flag
// word. Consumer w0: wave-parallel poll (one producer per lane, s_sleep).
__global__ __launch_bounds__(256, 2) void gru_persist(
    const uint4* __restrict__ Wimg, const int* __restrict__ tokm,
    const float* __restrict__ P2, const float* __restrict__ gbf,
    u64* __restrict__ exch, u16* __restrict__ Hout,
    int* __restrict__ flags) {
  int bid = blockIdx.x;
  int gt = bid & 7, ds = bid >> 3;
  int tid = threadIdx.x;
  int w = tid >> 6, lane = tid & 63;

  __shared__ float red[4][64][13];
  __shared__ u16 tr[256];
  __shared__ float Pl[3][16][49];
  __shared__ int tokL[16 * 259];       // stride 259: conflict-free token reads

  // persistent B fragments: 3 gates x 8 k-steps (this wave's K-quarter)
  f16x8 breg[3][8];
  {
    const uint4* wsrc = Wimg + (size_t)ds * 96 * 64 + lane;
    #pragma unroll
    for (int k8 = 0; k8 < 8; ++k8)
      #pragma unroll
      for (int g = 0; g < 3; ++g)
        breg[g][k8] = __builtin_bit_cast(f16x8, wsrc[((w * 8 + k8) * 3 + g) * 64]);
  }

  // preload epilogue tables: P2 slice (3x16x41) and token map (16x256)
  for (int i = tid; i < 3 * 16 * VOCAB; i += 256) {
    int v = i % VOCAB;
    int t1 = i / VOCAB;
    int di = t1 & 15, g = t1 >> 4;
    Pl[g][di][v] = P2[(size_t)(g * 1024 + ds * 16 + di) * VOCAB + v];
  }
  for (int i = tid; i < 16 * 256; i += 256) {
    int rr = i >> 8, cc = i & 255;
    tokL[rr * 259 + cc] = tokm[gt * 4096 + i];
  }

  // per-thread epilogue ownership: one (row, dim) pair
  int row = tid >> 4, dim = tid & 15;
  int lane_src = (row >> 2) * 16 + dim;
  int rg = row & 3;
  float b1h = gbf[H3 + 2048 + ds * 16 + dim];
  float hcur = 0.f;
  int ks_blk = ds >> 1, q0 = (ds & 1) * 2;
  int* flc = flags + gt * 1024;        // 64 producers x 16-int stride

  for (int t = 0; t < TT; ++t) {
    if (t > 0 && w == 0) poll_flags(flc, lane, t);
    __syncthreads();                                   // S1

    // A loads: this wave's K-quarter of the 16-row tile, from slot t&7
    const u64* abase = exch + (size_t)(t & 7) * SLOT_U64 + gt * 4096 +
                       (w * 8) * 128 + lane * 2;
    u64 av[16];
    #pragma unroll
    for (int i = 0; i < 8; ++i) {
      av[2 * i]     = aload64(abase + i * 128);
      av[2 * i + 1] = aload64(abase + i * 128 + 1);
    }
    f32x4 acc0 = {0.f, 0.f, 0.f, 0.f};
    f32x4 acc1 = {0.f, 0.f, 0.f, 0.f};
    f32x4 acc2 = {0.f, 0.f, 0.f, 0.f};
    #pragma unroll
    for (int k8 = 0; k8 < 8; ++k8) {
      u64x2 pair; pair.x = av[2 * k8]; pair.y = av[2 * k8 + 1];
      f16x8 a = __builtin_bit_cast(f16x8, pair);
      acc0 = __builtin_amdgcn_mfma_f32_16x16x32_f16(a, breg[0][k8], acc0, 0, 0, 0);
      acc1 = __builtin_amdgcn_mfma_f32_16x16x32_f16(a, breg[1][k8], acc1, 0, 0, 0);
      acc2 = __builtin_amdgcn_mfma_f32_16x16x32_f16(a, breg[2][k8], acc2, 0, 0, 0);
    }

    {
      float* q = red[w][lane];
      q[0] = acc0[0]; q[1] = acc0[1]; q[2]  = acc0[2]; q[3]  = acc0[3];
      q[4] = acc1[0]; q[5] = acc1[1]; q[6]  = acc1[2]; q[7]  = acc1[3];
      q[8] = acc2[0]; q[9] = acc2[1]; q[10] = acc2[2]; q[11] = acc2[3];
    }
    __syncthreads();                                   // S2

    // per-thread reduce over 4 K-quarters + gate epilogue
    {
      float a0 = 0.f, a1 = 0.f, a2 = 0.f;
      #pragma unroll
      for (int ww = 0; ww < 4; ++ww) {
        const float* q = red[ww][lane_src];
        a0 += q[rg]; a1 += q[4 + rg]; a2 += q[8 + rg];
      }
      int tm = tokL[row * 259 + t];
      int tok = tm & 0xFFFF;
      float z  = sigmoidf_(Pl[0][dim][tok] + a0);
      float r_ = sigmoidf_(Pl[1][dim][tok] + a1);
      float hh = tanh_fast(Pl[2][dim][tok] + r_ * (a2 + b1h));
      if (tm >= 0) hcur = z * hcur + (1.0f - z) * hh;
      tr[(dim >> 3) * 128 + row * 8 + (dim & 7)] = f2h_bits(hcur);
    }
    __syncthreads();                                   // S3

    if (w == 0) {
      u64 v = ((const u64*)tr)[lane];
      astore64(exch + (size_t)((t + 1) & 7) * SLOT_U64 + gt * 4096 +
                   ks_blk * 128 + q0 * 32 + lane, v);
      __atomic_signal_fence(__ATOMIC_SEQ_CST);
      __builtin_amdgcn_s_waitcnt(0);                   // exch at coherence pt
      __atomic_signal_fence(__ATOMIC_SEQ_CST);
      if (lane == 0)
        __hip_atomic_fetch_add(flc + ds * 16, 1, __ATOMIC_RELAXED,
                               __HIP_MEMORY_SCOPE_AGENT);
      // Hout store off the critical path (visible at kernel completion)
      if (lane < 32) {
        int qq = lane >> 4, mm = lane & 15;
        uint4 hv = ((const uint4*)tr)[lane];
        int b = gt * 16 + mm;
        size_t idx = ((size_t)(b * 16 + (t >> 4)) * 32 + ks_blk) * 64 +
                     (q0 + qq) * 16 + (t & 15);
        ((uint4*)Hout)[idx] = hv;
      }
    }
  }
}

// ---------- dense epilogue (r8-identical) ----------
__global__ __launch_bounds__(256) void dense_mfma(
    const u16* __restrict__ HoutImg, const uint4* __restrict__ dimg,
    const float* __restrict__ dbf, void* __restrict__ out,
    const int* __restrict__ flag) {
  __shared__ uint4 Bl[48 * 64];
  int tid = threadIdx.x;
  int w = tid >> 6, lane = tid & 63;
  int quad = lane >> 4, vi = lane & 15;
  int gt0 = blockIdx.x * 8 + w * 2;

  f32x4 acc[2][3];
  #pragma unroll
  for (int i = 0; i < 2; ++i)
    #pragma unroll
    for (int c = 0; c < 3; ++c) acc[i][c] = (f32x4){0.f, 0.f, 0.f, 0.f};

  for (int half = 0; half < 2; ++half) {
    for (int i = tid; i < 48 * 64; i += 256) Bl[i] = dimg[half * 48 * 64 + i];
    __syncthreads();
    #pragma unroll
    for (int ks16 = 0; ks16 < 16; ++ks16) {
      int ks = half * 16 + ks16;
      f16x8 a0 = __builtin_bit_cast(
          f16x8, ((const uint4*)HoutImg)[((size_t)gt0 * 32 + ks) * 64 + lane]);
      f16x8 a1 = __builtin_bit_cast(
          f16x8, ((const uint4*)HoutImg)[(((size_t)gt0 + 1) * 32 + ks) * 64 + lane]);
      #pragma unroll
      for (int c = 0; c < 3; ++c) {
        f16x8 bf = __builtin_bit_cast(f16x8, Bl[(ks16 * 3 + c) * 64 + lane]);
        acc[0][c] = __builtin_amdgcn_mfma_f32_16x16x32_f16(a0, bf, acc[0][c], 0, 0, 0);
        acc[1][c] = __builtin_amdgcn_mfma_f32_16x16x32_f16(a1, bf, acc[1][c], 0, 0, 0);
      }
    }
    __syncthreads();
  }

  int isf = *flag;
  #pragma unroll
  for (int i = 0; i < 2; ++i) {
    #pragma unroll
    for (int c = 0; c < 3; ++c) {
      int v = c * 16 + vi;
      if (v >= VOCAB) continue;
      float bias = dbf[v];
      #pragma unroll
      for (int rg = 0; rg < 4; ++rg) {
        size_t bt = (size_t)(gt0 + i) * 16 + quad * 4 + rg;
        float val = acc[i][c][rg] + bias;
        if (isf) ((float*)out)[bt * VOCAB + v] = val;
        else     ((u16*)out)[bt * VOCAB + v] = f2bf(val);
      }
    }
  }
}

// ---------- launch ----------

extern "C" void kernel_launch(void* const* d_in, const int* in_sizes, int n_in,
                              void* d_out, int out_size, void* d_ws, size_t ws_size,
                              hipStream_t stream) {
  const int* x            = (const int*)d_in[0];
  const unsigned char* mk = (const unsigned char*)d_in[1];

  char* ws = (char*)d_ws;
  int*   flag  = (int*)(ws + 0);
  float* dbf   = (float*)(ws + 4 * 1024);
  float* gbf   = (float*)(ws + 8 * 1024);            // 24 KB
  int*   flags = (int*)(ws + 32 * 1024);             // 8*64*16*4 = 32 KB
  int*   tokm  = (int*)(ws + 64 * 1024);             // 128 KB
  u16*   dimg  = (u16*)(ws + 192 * 1024);            // 96 KB
  float* P     = (float*)(ws + 288 * 1024);          // 504 KB
  float* P2    = (float*)(ws + 800 * 1024);          // 504 KB
  u64*   exch  = (u64*)(ws + 1312 * 1024);           // 2 MB (8 slots x 256 KB)
  u16*   Wimg  = (u16*)(ws + 3456 * 1024);           // 6 MB
  u16*   Hout  = (u16*)(ws + 10 * 1024 * 1024);      // 64 MB

  detect_kernel<<<1, 256, 0, stream>>>((const u16*)d_in[4], flag);
  conv_kernel<<<(2 * H3 + 255) / 256, 256, 0, stream>>>(d_in[5], gbf, 2 * H3, flag);
  conv_kernel<<<1, 256, 0, stream>>>(d_in[7], dbf, VOCAB, flag);
  tokm_kernel<<<BT / 256, 256, 0, stream>>>(x, mk, tokm);
  proj_kernel<<<VOCAB * (H3 / 256), 256, 0, stream>>>(d_in[2], d_in[3], gbf, P, flag);
  p2_kernel<<<H3, 64, 0, stream>>>(P, gbf, P2);
  pack_wimg_kernel<<<(64 * 32 * 3 * 64 * 8) / 256, 256, 0, stream>>>(d_in[4], Wimg, flag);
  pack_dimg_kernel<<<(32 * 3 * 64 * 8) / 256, 256, 0, stream>>>(d_in[6], dimg, flag);
  hipMemsetAsync(flags, 0, 32 * 1024, stream);
  hipMemsetAsync(exch, 0, SLOT_U64 * 8, stream);     // slot 0 = h_0 = zeros

  gru_persist<<<512, 256, 0, stream>>>((const uint4*)Wimg, tokm, P2, gbf,
                                       exch, Hout, flags);
  dense_mfma<<<256, 256, 0, stream>>>(Hout, (const uint4*)dimg, dbf, d_out, flag);
}

// Round 13
// 1204.006 us; speedup vs baseline: 2.6665x; 1.0041x over previous
//
#include <hip/hip_runtime.h>
#include <stdint.h>
#include <stddef.h>

#define VOCAB 41
#define EMB   512
#define HID   1024
#define H3    3072
#define BB    128
#define TT    256
#define BT    (BB*TT)
#define NSLOT 8
#define SLOT_U64 32768        // 256 KB per slot

typedef unsigned short u16;
typedef _Float16 half_t;
typedef half_t f16x8 __attribute__((ext_vector_type(8)));
typedef float f32x4 __attribute__((ext_vector_type(4)));
typedef unsigned long long u64;
typedef u64 u64x2 __attribute__((ext_vector_type(2)));

__device__ __forceinline__ float bf2f(u16 u) {
  return __uint_as_float(((uint32_t)u) << 16);
}
__device__ __forceinline__ u16 f2bf(float f) {
  uint32_t x = __float_as_uint(f);
  return (u16)((x + 0x7FFFu + ((x >> 16) & 1u)) >> 16);
}
__device__ __forceinline__ u16 f2h_bits(float f) {
  half_t h = (half_t)f;
  return __builtin_bit_cast(u16, h);
}
__device__ __forceinline__ float sigmoidf_(float x) {
  return 1.0f / (1.0f + __expf(-x));
}
__device__ __forceinline__ float tanh_fast(float x) {
  return 1.0f - 2.0f / (__expf(2.0f * x) + 1.0f);
}
__device__ __forceinline__ u64 aload64(const u64* p) {
  return __hip_atomic_load(p, __ATOMIC_RELAXED, __HIP_MEMORY_SCOPE_AGENT);
}
__device__ __forceinline__ void astore64(u64* p, u64 v) {
  __hip_atomic_store(p, v, __ATOMIC_RELAXED, __HIP_MEMORY_SCOPE_AGENT);
}
// Wave-parallel poll of THIS WAVE's 16 producers (4 lanes share each flag;
// same-address loads broadcast). Flags stay 64B-padded per producer (r11
// proved packing serializes the producer RMWs).
__device__ __forceinline__ void poll_flags16(const int* flc, int idx, int target) {
  int cap = 0;
  while (true) {
    int v = __hip_atomic_load(flc + idx * 16, __ATOMIC_RELAXED,
                              __HIP_MEMORY_SCOPE_AGENT);
    if (__ballot(v < target) == 0ULL) break;
    __builtin_amdgcn_s_sleep(1);
    if (++cap > (1 << 16)) break;   // fail fast instead of hanging
  }
}

// ---------- prologue kernels (r12-identical) ----------

__global__ void detect_kernel(const u16* __restrict__ raw, int* __restrict__ flag) {
  __shared__ int s[256];
  int tid = threadIdx.x, cnt = 0;
  for (int i = tid; i < 4096; i += 256) {
    int e = (raw[i] >> 7) & 0xFF;
    if (e >= 132) cnt++;
  }
  s[tid] = cnt; __syncthreads();
  if (tid == 0) {
    int tot = 0;
    for (int i = 0; i < 256; i++) tot += s[i];
    *flag = (tot > 4) ? 1 : 0;
  }
}

__global__ void conv_kernel(const void* __restrict__ src, float* __restrict__ dst,
                            int n, const int* __restrict__ flag) {
  int i = blockIdx.x * 256 + threadIdx.x;
  if (i >= n) return;
  if (*flag) dst[i] = ((const float*)src)[i];
  else       dst[i] = bf2f(((const u16*)src)[i]);
}

__global__ void tokm_kernel(const int* __restrict__ x,
                            const unsigned char* __restrict__ m,
                            int* __restrict__ tokm) {
  int i = blockIdx.x * 256 + threadIdx.x;
  unsigned char b0 = m[0], b1 = m[1];
  bool t;
  if (b0 == 1) {
    if (b1 != 0) t = (m[i] != 0);
    else         t = (((const int*)m)[i] != 0);
  } else if (b0 == 0x80) {
    t = (((const u16*)m)[i] != 0);
  } else {
    t = (((const float*)m)[i] != 0.0f);
  }
  tokm[i] = x[i] | (t ? 0 : 0x80000000);
}

__global__ __launch_bounds__(256) void proj_kernel(
    const void* __restrict__ emb, const void* __restrict__ gk,
    const float* __restrict__ gbf, float* __restrict__ P,
    const int* __restrict__ flag) {
  int v = blockIdx.x / (H3 / 256);
  int j = (blockIdx.x % (H3 / 256)) * 256 + threadIdx.x;
  float acc = gbf[j];
  if (*flag) {
    const float* e = (const float*)emb + v * EMB;
    const float* g = (const float*)gk;
    for (int k = 0; k < EMB; ++k) acc = fmaf(e[k], g[k * H3 + j], acc);
  } else {
    const u16* e = (const u16*)emb + v * EMB;
    const u16* g = (const u16*)gk;
    for (int k = 0; k < EMB; ++k) acc = fmaf(bf2f(e[k]), bf2f(g[k * H3 + j]), acc);
  }
  P[v * H3 + j] = acc;
}

__global__ void p2_kernel(const float* __restrict__ P, const float* __restrict__ gbf,
                          float* __restrict__ P2) {
  int gc = blockIdx.x;
  int v = threadIdx.x;
  if (v >= VOCAB) return;
  float val = P[v * H3 + gc];
  if (gc < 2048) val += gbf[H3 + gc];
  P2[gc * VOCAB + v] = val;
}

__global__ void pack_wimg_kernel(const void* __restrict__ src, u16* __restrict__ img,
                                 const int* __restrict__ flag) {
  int idx = blockIdx.x * 256 + threadIdx.x;
  int j = idx & 7;
  int t1 = idx >> 3;
  int lane = t1 & 63;
  int t2 = t1 >> 6;
  int g = t2 % 3;
  int t3 = t2 / 3;
  int ks = t3 & 31;
  int ds = t3 >> 5;
  int k = ks * 32 + (lane >> 4) * 8 + j;
  int col = g * 1024 + ds * 16 + (lane & 15);
  float val;
  if (*flag) val = ((const float*)src)[(size_t)k * H3 + col];
  else       val = bf2f(((const u16*)src)[(size_t)k * H3 + col]);
  img[idx] = f2h_bits(val);
}

__global__ void pack_dimg_kernel(const void* __restrict__ src, u16* __restrict__ img,
                                 const int* __restrict__ flag) {
  int idx = blockIdx.x * 256 + threadIdx.x;
  int j = idx & 7;
  int t1 = idx >> 3;
  int lane = t1 & 63;
  int t2 = t1 >> 6;
  int ct = t2 % 3;
  int ks = t2 / 3;
  int k = ks * 32 + (lane >> 4) * 8 + j;
  int v = ct * 16 + (lane & 15);
  float val = 0.0f;
  if (v < VOCAB) {
    if (*flag) val = ((const float*)src)[(size_t)k * VOCAB + v];
    else       val = bf2f(((const u16*)src)[(size_t)k * VOCAB + v]);
  }
  img[idx] = f2h_bits(val);
}

// ---------- persistent GRU: r8 signal protocol + per-wave 16-producer gate
// 512 blocks x 256 thr (2/CU). bid = ds*8 + gt. Block: 16 rows (gt) x
// 16 dims (ds), K split across 4 waves; W frags persistent in regs.
// Producer: exch stores -> vmcnt(0) drain -> atomicAdd on own PADDED flag.
// Consumer: EACH WAVE self-gates on only the 16 producers of its K-quarter
// (ds in [w*16, w*16+16)) -- no S1 barrier; S2/S3 order red/tr hazards.
__global__ __launch_bounds__(256, 2) void gru_persist(
    const uint4* __restrict__ Wimg, const int* __restrict__ tokm,
    const float* __restrict__ P2, const float* __restrict__ gbf,
    u64* __restrict__ exch, u16* __restrict__ Hout,
    int* __restrict__ flags) {
  int bid = blockIdx.x;
  int gt = bid & 7, ds = bid >> 3;
  int tid = threadIdx.x;
  int w = tid >> 6, lane = tid & 63;

  __shared__ float red[4][64][13];
  __shared__ u16 tr[256];
  __shared__ float Pl[3][16][49];
  __shared__ int tokL[16 * 259];       // stride 259: conflict-free token reads

  // persistent B fragments: 3 gates x 8 k-steps (this wave's K-quarter)
  f16x8 breg[3][8];
  {
    const uint4* wsrc = Wimg + (size_t)ds * 96 * 64 + lane;
    #pragma unroll
    for (int k8 = 0; k8 < 8; ++k8)
      #pragma unroll
      for (int g = 0; g < 3; ++g)
        breg[g][k8] = __builtin_bit_cast(f16x8, wsrc[((w * 8 + k8) * 3 + g) * 64]);
  }

  // preload epilogue tables: P2 slice (3x16x41) and token map (16x256)
  for (int i = tid; i < 3 * 16 * VOCAB; i += 256) {
    int v = i % VOCAB;
    int t1 = i / VOCAB;
    int di = t1 & 15, g = t1 >> 4;
    Pl[g][di][v] = P2[(size_t)(g * 1024 + ds * 16 + di) * VOCAB + v];
  }
  for (int i = tid; i < 16 * 256; i += 256) {
    int rr = i >> 8, cc = i & 255;
    tokL[rr * 259 + cc] = tokm[gt * 4096 + i];
  }

  // per-thread epilogue ownership: one (row, dim) pair
  int row = tid >> 4, dim = tid & 15;
  int lane_src = (row >> 2) * 16 + dim;
  int rg = row & 3;
  float b1h = gbf[H3 + 2048 + ds * 16 + dim];
  float hcur = 0.f;
  int ks_blk = ds >> 1, q0 = (ds & 1) * 2;
  int* flc = flags + gt * 1024;        // 64 producers x 16-int stride
  int widx = w * 16 + (lane & 15);     // this wave's watched producer
  __syncthreads();                     // protect LDS preloads (was S1 @ t=0)

  for (int t = 0; t < TT; ++t) {
    if (t > 0) poll_flags16(flc, widx, t);   // per-wave self-gate, no barrier

    // A loads: this wave's K-quarter of the 16-row tile, from slot t&7
    const u64* abase = exch + (size_t)(t & 7) * SLOT_U64 + gt * 4096 +
                       (w * 8) * 128 + lane * 2;
    u64 av[16];
    #pragma unroll
    for (int i = 0; i < 8; ++i) {
      av[2 * i]     = aload64(abase + i * 128);
      av[2 * i + 1] = aload64(abase + i * 128 + 1);
    }
    f32x4 acc0 = {0.f, 0.f, 0.f, 0.f};
    f32x4 acc1 = {0.f, 0.f, 0.f, 0.f};
    f32x4 acc2 = {0.f, 0.f, 0.f, 0.f};
    #pragma unroll
    for (int k8 = 0; k8 < 8; ++k8) {
      u64x2 pair; pair.x = av[2 * k8]; pair.y = av[2 * k8 + 1];
      f16x8 a = __builtin_bit_cast(f16x8, pair);
      acc0 = __builtin_amdgcn_mfma_f32_16x16x32_f16(a, breg[0][k8], acc0, 0, 0, 0);
      acc1 = __builtin_amdgcn_mfma_f32_16x16x32_f16(a, breg[1][k8], acc1, 0, 0, 0);
      acc2 = __builtin_amdgcn_mfma_f32_16x16x32_f16(a, breg[2][k8], acc2, 0, 0, 0);
    }

    {
      float* q = red[w][lane];
      q[0] = acc0[0]; q[1] = acc0[1]; q[2]  = acc0[2]; q[3]  = acc0[3];
      q[4] = acc1[0]; q[5] = acc1[1]; q[6]  = acc1[2]; q[7]  = acc1[3];
      q[8] = acc2[0]; q[9] = acc2[1]; q[10] = acc2[2]; q[11] = acc2[3];
    }
    __syncthreads();                                   // S2

    // per-thread reduce over 4 K-quarters + gate epilogue
    {
      float a0 = 0.f, a1 = 0.f, a2 = 0.f;
      #pragma unroll
      for (int ww = 0; ww < 4; ++ww) {
        const float* q = red[ww][lane_src];
        a0 += q[rg]; a1 += q[4 + rg]; a2 += q[8 + rg];
      }
      int tm = tokL[row * 259 + t];
      int tok = tm & 0xFFFF;
      float z  = sigmoidf_(Pl[0][dim][tok] + a0);
      float r_ = sigmoidf_(Pl[1][dim][tok] + a1);
      float hh = tanh_fast(Pl[2][dim][tok] + r_ * (a2 + b1h));
      if (tm >= 0) hcur = z * hcur + (1.0f - z) * hh;
      tr[(dim >> 3) * 128 + row * 8 + (dim & 7)] = f2h_bits(hcur);
    }
    __syncthreads();                                   // S3

    if (w == 0) {
      u64 v = ((const u64*)tr)[lane];
      astore64(exch + (size_t)((t + 1) & 7) * SLOT_U64 + gt * 4096 +
                   ks_blk * 128 + q0 * 32 + lane, v);
      __atomic_signal_fence(__ATOMIC_SEQ_CST);
      __builtin_amdgcn_s_waitcnt(0);                   // exch at coherence pt
      __atomic_signal_fence(__ATOMIC_SEQ_CST);
      if (lane == 0)
        __hip_atomic_fetch_add(flc + ds * 16, 1, __ATOMIC_RELAXED,
                               __HIP_MEMORY_SCOPE_AGENT);
      // Hout store off the critical path (visible at kernel completion)
      if (lane < 32) {
        int qq = lane >> 4, mm = lane & 15;
        uint4 hv = ((const uint4*)tr)[lane];
        int b = gt * 16 + mm;
        size_t idx = ((size_t)(b * 16 + (t >> 4)) * 32 + ks_blk) * 64 +
                     (q0 + qq) * 16 + (t & 15);
        ((uint4*)Hout)[idx] = hv;
      }
    }
  }
}

// ---------- dense epilogue (r12-identical) ----------
__global__ __launch_bounds__(256) void dense_mfma(
    const u16* __restrict__ HoutImg, const uint4* __restrict__ dimg,
    const float* __restrict__ dbf, void* __restrict__ out,
    const int* __restrict__ flag) {
  __shared__ uint4 Bl[48 * 64];
  int tid = threadIdx.x;
  int w = tid >> 6, lane = tid & 63;
  int quad = lane >> 4, vi = lane & 15;
  int gt0 = blockIdx.x * 8 + w * 2;

  f32x4 acc[2][3];
  #pragma unroll
  for (int i = 0; i < 2; ++i)
    #pragma unroll
    for (int c = 0; c < 3; ++c) acc[i][c] = (f32x4){0.f, 0.f, 0.f, 0.f};

  for (int half = 0; half < 2; ++half) {
    for (int i = tid; i < 48 * 64; i += 256) Bl[i] = dimg[half * 48 * 64 + i];
    __syncthreads();
    #pragma unroll
    for (int ks16 = 0; ks16 < 16; ++ks16) {
      int ks = half * 16 + ks16;
      f16x8 a0 = __builtin_bit_cast(
          f16x8, ((const uint4*)HoutImg)[((size_t)gt0 * 32 + ks) * 64 + lane]);
      f16x8 a1 = __builtin_bit_cast(
          f16x8, ((const uint4*)HoutImg)[(((size_t)gt0 + 1) * 32 + ks) * 64 + lane]);
      #pragma unroll
      for (int c = 0; c < 3; ++c) {
        f16x8 bf = __builtin_bit_cast(f16x8, Bl[(ks16 * 3 + c) * 64 + lane]);
        acc[0][c] = __builtin_amdgcn_mfma_f32_16x16x32_f16(a0, bf, acc[0][c], 0, 0, 0);
        acc[1][c] = __builtin_amdgcn_mfma_f32_16x16x32_f16(a1, bf, acc[1][c], 0, 0, 0);
      }
    }
    __syncthreads();
  }

  int isf = *flag;
  #pragma unroll
  for (int i = 0; i < 2; ++i) {
    #pragma unroll
    for (int c = 0; c < 3; ++c) {
      int v = c * 16 + vi;
      if (v >= VOCAB) continue;
      float bias = dbf[v];
      #pragma unroll
      for (int rg = 0; rg < 4; ++rg) {
        size_t bt = (size_t)(gt0 + i) * 16 + quad * 4 + rg;
        float val = acc[i][c][rg] + bias;
        if (isf) ((float*)out)[bt * VOCAB + v] = val;
        else     ((u16*)out)[bt * VOCAB + v] = f2bf(val);
      }
    }
  }
}

// ---------- launch ----------

extern "C" void kernel_launch(void* const* d_in, const int* in_sizes, int n_in,
                              void* d_out, int out_size, void* d_ws, size_t ws_size,
                              hipStream_t stream) {
  const int* x            = (const int*)d_in[0];
  const unsigned char* mk = (const unsigned char*)d_in[1];

  char* ws = (char*)d_ws;
  int*   flag  = (int*)(ws + 0);
  float* dbf   = (float*)(ws + 4 * 1024);
  float* gbf   = (float*)(ws + 8 * 1024);            // 24 KB
  int*   flags = (int*)(ws + 32 * 1024);             // 8*64*16*4 = 32 KB
  int*   tokm  = (int*)(ws + 64 * 1024);             // 128 KB
  u16*   dimg  = (u16*)(ws + 192 * 1024);            // 96 KB
  float* P     = (float*)(ws + 288 * 1024);          // 504 KB
  float* P2    = (float*)(ws + 800 * 1024);          // 504 KB
  u64*   exch  = (u64*)(ws + 1312 * 1024);           // 2 MB (8 slots x 256 KB)
  u16*   Wimg  = (u16*)(ws + 3456 * 1024);           // 6 MB
  u16*   Hout  = (u16*)(ws + 10 * 1024 * 1024);      // 64 MB

  detect_kernel<<<1, 256, 0, stream>>>((const u16*)d_in[4], flag);
  conv_kernel<<<(2 * H3 + 255) / 256, 256, 0, stream>>>(d_in[5], gbf, 2 * H3, flag);
  conv_kernel<<<1, 256, 0, stream>>>(d_in[7], dbf, VOCAB, flag);
  tokm_kernel<<<BT / 256, 256, 0, stream>>>(x, mk, tokm);
  proj_kernel<<<VOCAB * (H3 / 256), 256, 0, stream>>>(d_in[2], d_in[3], gbf, P, flag);
  p2_kernel<<<H3, 64, 0, stream>>>(P, gbf, P2);
  pack_wimg_kernel<<<(64 * 32 * 3 * 64 * 8) / 256, 256, 0, stream>>>(d_in[4], Wimg, flag);
  pack_dimg_kernel<<<(32 * 3 * 64 * 8) / 256, 256, 0, stream>>>(d_in[6], dimg, flag);
  hipMemsetAsync(flags, 0, 32 * 1024, stream);
  hipMemsetAsync(exch, 0, SLOT_U64 * 8, stream);     // slot 0 = h_0 = zeros

  gru_persist<<<512, 256, 0, stream>>>((const uint4*)Wimg, tokm, P2, gbf,
                                       exch, Hout, flags);
  dense_mfma<<<256, 256, 0, stream>>>(Hout, (const uint4*)dimg, dbf, d_out, flag);
}

// Round 14
// 995.701 us; speedup vs baseline: 3.2243x; 1.2092x over previous
//
#include <hip/hip_runtime.h>
#include <stdint.h>
#include <stddef.h>

#define VOCAB 41
#define EMB   512
#define HID   1024
#define H3    3072
#define BB    128
#define TT    256
#define BT    (BB*TT)
#define NSLOT 8
#define SLOT_U64 32768        // 256 KB per slot

typedef unsigned short u16;
typedef _Float16 half_t;
typedef half_t f16x8 __attribute__((ext_vector_type(8)));
typedef float f32x4 __attribute__((ext_vector_type(4)));
typedef unsigned long long u64;
typedef u64 u64x2 __attribute__((ext_vector_type(2)));

__device__ __forceinline__ float bf2f(u16 u) {
  return __uint_as_float(((uint32_t)u) << 16);
}
__device__ __forceinline__ u16 f2bf(float f) {
  uint32_t x = __float_as_uint(f);
  return (u16)((x + 0x7FFFu + ((x >> 16) & 1u)) >> 16);
}
__device__ __forceinline__ u16 f2h_bits(float f) {
  half_t h = (half_t)f;
  return __builtin_bit_cast(u16, h);
}
__device__ __forceinline__ float sigmoidf_(float x) {
  return 1.0f / (1.0f + __expf(-x));
}
__device__ __forceinline__ float tanh_fast(float x) {
  return 1.0f - 2.0f / (__expf(2.0f * x) + 1.0f);
}
__device__ __forceinline__ u64 aload64(const u64* p) {
  return __hip_atomic_load(p, __ATOMIC_RELAXED, __HIP_MEMORY_SCOPE_AGENT);
}
__device__ __forceinline__ void astore64(u64* p, u64 v) {
  __hip_atomic_store(p, v, __ATOMIC_RELAXED, __HIP_MEMORY_SCOPE_AGENT);
}
// Wave-parallel poll of THIS WAVE's 8 producers (8 lanes share each flag;
// same-address loads broadcast). Flags 64B-padded per producer (r11 proved
// packing serializes the producer RMWs -- keep the padding).
__device__ __forceinline__ void poll_flags8(const int* flc, int idx, int target) {
  int cap = 0;
  while (true) {
    int v = __hip_atomic_load(flc + idx * 16, __ATOMIC_RELAXED,
                              __HIP_MEMORY_SCOPE_AGENT);
    if (__ballot(v < target) == 0ULL) break;
    __builtin_amdgcn_s_sleep(1);
    if (++cap > (1 << 16)) break;   // fail fast instead of hanging
  }
}

// ---------- prologue kernels ----------

__global__ void detect_kernel(const u16* __restrict__ raw, int* __restrict__ flag) {
  __shared__ int s[256];
  int tid = threadIdx.x, cnt = 0;
  for (int i = tid; i < 4096; i += 256) {
    int e = (raw[i] >> 7) & 0xFF;
    if (e >= 132) cnt++;
  }
  s[tid] = cnt; __syncthreads();
  if (tid == 0) {
    int tot = 0;
    for (int i = 0; i < 256; i++) tot += s[i];
    *flag = (tot > 4) ? 1 : 0;
  }
}

__global__ void conv_kernel(const void* __restrict__ src, float* __restrict__ dst,
                            int n, const int* __restrict__ flag) {
  int i = blockIdx.x * 256 + threadIdx.x;
  if (i >= n) return;
  if (*flag) dst[i] = ((const float*)src)[i];
  else       dst[i] = bf2f(((const u16*)src)[i]);
}

__global__ void tokm_kernel(const int* __restrict__ x,
                            const unsigned char* __restrict__ m,
                            int* __restrict__ tokm) {
  int i = blockIdx.x * 256 + threadIdx.x;
  unsigned char b0 = m[0], b1 = m[1];
  bool t;
  if (b0 == 1) {
    if (b1 != 0) t = (m[i] != 0);
    else         t = (((const int*)m)[i] != 0);
  } else if (b0 == 0x80) {
    t = (((const u16*)m)[i] != 0);
  } else {
    t = (((const float*)m)[i] != 0.0f);
  }
  tokm[i] = x[i] | (t ? 0 : 0x80000000);
}

__global__ __launch_bounds__(256) void proj_kernel(
    const void* __restrict__ emb, const void* __restrict__ gk,
    const float* __restrict__ gbf, float* __restrict__ P,
    const int* __restrict__ flag) {
  int v = blockIdx.x / (H3 / 256);
  int j = (blockIdx.x % (H3 / 256)) * 256 + threadIdx.x;
  float acc = gbf[j];
  if (*flag) {
    const float* e = (const float*)emb + v * EMB;
    const float* g = (const float*)gk;
    for (int k = 0; k < EMB; ++k) acc = fmaf(e[k], g[k * H3 + j], acc);
  } else {
    const u16* e = (const u16*)emb + v * EMB;
    const u16* g = (const u16*)gk;
    for (int k = 0; k < EMB; ++k) acc = fmaf(bf2f(e[k]), bf2f(g[k * H3 + j]), acc);
  }
  P[v * H3 + j] = acc;
}

__global__ void p2_kernel(const float* __restrict__ P, const float* __restrict__ gbf,
                          float* __restrict__ P2) {
  int gc = blockIdx.x;
  int v = threadIdx.x;
  if (v >= VOCAB) return;
  float val = P[v * H3 + gc];
  if (gc < 2048) val += gbf[H3 + gc];
  P2[gc * VOCAB + v] = val;
}

// Fat-block Wimg: [ds 0..31][ks 0..31][c 0..5][lane][j], c = g*2 + dh,
// col = g*1024 + ds*32 + dh*16 + (lane&15), k = ks*32 + (lane>>4)*8 + j.
__global__ void pack_wimg_kernel(const void* __restrict__ src, u16* __restrict__ img,
                                 const int* __restrict__ flag) {
  int idx = blockIdx.x * 256 + threadIdx.x;       // 0 .. 3,145,727
  int j = idx & 7;
  int t1 = idx >> 3;
  int lane = t1 & 63;
  int t2 = t1 >> 6;
  int c = t2 % 6;
  int t3 = t2 / 6;
  int ks = t3 & 31;
  int ds = t3 >> 5;
  int g = c >> 1, dh = c & 1;
  int k = ks * 32 + (lane >> 4) * 8 + j;
  int col = g * 1024 + ds * 32 + dh * 16 + (lane & 15);
  float val;
  if (*flag) val = ((const float*)src)[(size_t)k * H3 + col];
  else       val = bf2f(((const u16*)src)[(size_t)k * H3 + col]);
  img[idx] = f2h_bits(val);
}

__global__ void pack_dimg_kernel(const void* __restrict__ src, u16* __restrict__ img,
                                 const int* __restrict__ flag) {
  int idx = blockIdx.x * 256 + threadIdx.x;
  int j = idx & 7;
  int t1 = idx >> 3;
  int lane = t1 & 63;
  int t2 = t1 >> 6;
  int ct = t2 % 3;
  int ks = t2 / 3;
  int k = ks * 32 + (lane >> 4) * 8 + j;
  int v = ct * 16 + (lane & 15);
  float val = 0.0f;
  if (v < VOCAB) {
    if (*flag) val = ((const float*)src)[(size_t)k * VOCAB + v];
    else       val = bf2f(((const u16*)src)[(size_t)k * VOCAB + v]);
  }
  img[idx] = f2h_bits(val);
}

// ---------- persistent GRU: fat blocks (32 dims), r8 signal protocol ------
// 256 blocks x 256 thr (1/CU, exactly co-resident). bid = ds*8 + gt.
// Block: 16 rows (gt) x 32 dims (ds = k-step ds), K split across 4 waves;
// 6 acc tiles/wave, breg 192 VGPR (launch_bounds(256,1) -> 512 budget).
// Producer: exch stores -> vmcnt(0) drain -> atomicAdd on own PADDED flag.
// Consumer: each wave self-gates on only its 8 K-quarter producers.
__global__ __launch_bounds__(256, 1) void gru_persist(
    const uint4* __restrict__ Wimg, const int* __restrict__ tokm,
    const float* __restrict__ P2, const float* __restrict__ gbf,
    u64* __restrict__ exch, u16* __restrict__ Hout,
    int* __restrict__ flags) {
  int bid = blockIdx.x;
  int gt = bid & 7, ds = bid >> 3;     // ds 0..31
  int tid = threadIdx.x;
  int w = tid >> 6, lane = tid & 63;

  __shared__ float red[4][64][25];     // 24 acc floats/lane, pad 25
  __shared__ u16 tr[512];              // 16 rows x 32 dims
  __shared__ float Pl[3][32][41];
  __shared__ int tokL[16 * 259];

  // persistent B fragments: 6 tiles x 8 k-steps (this wave's K-quarter)
  f16x8 breg[6][8];
  {
    const uint4* wsrc = Wimg + (size_t)ds * (32 * 6) * 64 + lane;
    #pragma unroll
    for (int k8 = 0; k8 < 8; ++k8)
      #pragma unroll
      for (int c = 0; c < 6; ++c)
        breg[c][k8] = __builtin_bit_cast(f16x8, wsrc[((w * 8 + k8) * 6 + c) * 64]);
  }

  // preload epilogue tables: P2 slice (3x32x41) and token map (16x256)
  for (int i = tid; i < 3 * 32 * VOCAB; i += 256) {
    int v = i % VOCAB;
    int t1 = i / VOCAB;
    int di = t1 & 31, g = t1 >> 5;
    Pl[g][di][v] = P2[(size_t)(g * 1024 + ds * 32 + di) * VOCAB + v];
  }
  for (int i = tid; i < 16 * 256; i += 256) {
    int rr = i >> 8, cc = i & 255;
    tokL[rr * 259 + cc] = tokm[gt * 4096 + i];
  }

  // per-thread epilogue ownership: (row, dimb) and (row, dimb+16)
  int row = tid >> 4, dimb = tid & 15;
  int lane_src = (row >> 2) * 16 + dimb;
  int rg = row & 3;
  float b1h0 = gbf[H3 + 2048 + ds * 32 + dimb];
  float b1h1 = gbf[H3 + 2048 + ds * 32 + dimb + 16];
  float hc0 = 0.f, hc1 = 0.f;
  int* flc = flags + gt * 512;         // 32 producers x 16-int stride
  int widx = w * 8 + (lane & 7);       // this wave's watched producer
  __syncthreads();                     // protect LDS preloads

  for (int t = 0; t < TT; ++t) {
    if (t > 0) poll_flags8(flc, widx, t);    // per-wave self-gate

    // A loads: this wave's K-quarter (k-steps w*8..w*8+7), slot t&7
    const u64* abase = exch + (size_t)(t & 7) * SLOT_U64 + gt * 4096 +
                       (w * 8) * 128 + lane * 2;
    u64 av[16];
    #pragma unroll
    for (int i = 0; i < 8; ++i) {
      av[2 * i]     = aload64(abase + i * 128);
      av[2 * i + 1] = aload64(abase + i * 128 + 1);
    }
    f32x4 acc[6];
    #pragma unroll
    for (int c = 0; c < 6; ++c) acc[c] = (f32x4){0.f, 0.f, 0.f, 0.f};
    #pragma unroll
    for (int k8 = 0; k8 < 8; ++k8) {
      u64x2 pair; pair.x = av[2 * k8]; pair.y = av[2 * k8 + 1];
      f16x8 a = __builtin_bit_cast(f16x8, pair);
      #pragma unroll
      for (int c = 0; c < 6; ++c)
        acc[c] = __builtin_amdgcn_mfma_f32_16x16x32_f16(a, breg[c][k8], acc[c], 0, 0, 0);
    }

    {
      float* q = red[w][lane];
      #pragma unroll
      for (int c = 0; c < 6; ++c)
        #pragma unroll
        for (int r = 0; r < 4; ++r) q[c * 4 + r] = acc[c][r];
    }
    __syncthreads();                                   // S2

    // per-thread reduce over 4 K-quarters + gate epilogue (2 dims)
    {
      int tm = tokL[row * 259 + t];
      int tok = tm & 0xFFFF;
      #pragma unroll
      for (int dh = 0; dh < 2; ++dh) {
        float a0 = 0.f, a1 = 0.f, a2 = 0.f;
        #pragma unroll
        for (int ww = 0; ww < 4; ++ww) {
          const float* q = red[ww][lane_src];
          a0 += q[(0 * 2 + dh) * 4 + rg];
          a1 += q[(1 * 2 + dh) * 4 + rg];
          a2 += q[(2 * 2 + dh) * 4 + rg];
        }
        int dglob = dimb + dh * 16;
        float z  = sigmoidf_(Pl[0][dglob][tok] + a0);
        float r_ = sigmoidf_(Pl[1][dglob][tok] + a1);
        float b1h = dh ? b1h1 : b1h0;
        float hh = tanh_fast(Pl[2][dglob][tok] + r_ * (a2 + b1h));
        float h = dh ? hc1 : hc0;
        if (tm >= 0) h = z * h + (1.0f - z) * hh;
        if (dh) hc1 = h; else hc0 = h;
        tr[(dglob >> 3) * 128 + row * 8 + (dglob & 7)] = f2h_bits(h);
      }
    }
    __syncthreads();                                   // S3

    if (w == 0) {
      u64 v0 = ((const u64*)tr)[lane];
      u64 v1 = ((const u64*)tr)[lane + 64];
      u64* ebase = exch + (size_t)((t + 1) & 7) * SLOT_U64 + gt * 4096 +
                   ds * 128;
      astore64(ebase + lane, v0);
      astore64(ebase + 64 + lane, v1);
      __atomic_signal_fence(__ATOMIC_SEQ_CST);
      __builtin_amdgcn_s_waitcnt(0);                   // exch at coherence pt
      __atomic_signal_fence(__ATOMIC_SEQ_CST);
      if (lane == 0)
        __hip_atomic_fetch_add(flc + ds * 16, 1, __ATOMIC_RELAXED,
                               __HIP_MEMORY_SCOPE_AGENT);
      // Hout store off the critical path (visible at kernel completion)
      {
        int quad = lane >> 4, mm = lane & 15;
        uint4 hv = ((const uint4*)tr)[lane];
        int b = gt * 16 + mm;
        size_t idx = ((size_t)(b * 16 + (t >> 4)) * 32 + ds) * 64 +
                     quad * 16 + (t & 15);
        ((uint4*)Hout)[idx] = hv;
      }
    }
  }
}

// ---------- dense epilogue (unchanged; Hout layout identical) ----------
__global__ __launch_bounds__(256) void dense_mfma(
    const u16* __restrict__ HoutImg, const uint4* __restrict__ dimg,
    const float* __restrict__ dbf, void* __restrict__ out,
    const int* __restrict__ flag) {
  __shared__ uint4 Bl[48 * 64];
  int tid = threadIdx.x;
  int w = tid >> 6, lane = tid & 63;
  int quad = lane >> 4, vi = lane & 15;
  int gt0 = blockIdx.x * 8 + w * 2;

  f32x4 acc[2][3];
  #pragma unroll
  for (int i = 0; i < 2; ++i)
    #pragma unroll
    for (int c = 0; c < 3; ++c) acc[i][c] = (f32x4){0.f, 0.f, 0.f, 0.f};

  for (int half = 0; half < 2; ++half) {
    for (int i = tid; i < 48 * 64; i += 256) Bl[i] = dimg[half * 48 * 64 + i];
    __syncthreads();
    #pragma unroll
    for (int ks16 = 0; ks16 < 16; ++ks16) {
      int ks = half * 16 + ks16;
      f16x8 a0 = __builtin_bit_cast(
          f16x8, ((const uint4*)HoutImg)[((size_t)gt0 * 32 + ks) * 64 + lane]);
      f16x8 a1 = __builtin_bit_cast(
          f16x8, ((const uint4*)HoutImg)[(((size_t)gt0 + 1) * 32 + ks) * 64 + lane]);
      #pragma unroll
      for (int c = 0; c < 3; ++c) {
        f16x8 bf = __builtin_bit_cast(f16x8, Bl[(ks16 * 3 + c) * 64 + lane]);
        acc[0][c] = __builtin_amdgcn_mfma_f32_16x16x32_f16(a0, bf, acc[0][c], 0, 0, 0);
        acc[1][c] = __builtin_amdgcn_mfma_f32_16x16x32_f16(a1, bf, acc[1][c], 0, 0, 0);
      }
    }
    __syncthreads();
  }

  int isf = *flag;
  #pragma unroll
  for (int i = 0; i < 2; ++i) {
    #pragma unroll
    for (int c = 0; c < 3; ++c) {
      int v = c * 16 + vi;
      if (v >= VOCAB) continue;
      float bias = dbf[v];
      #pragma unroll
      for (int rg = 0; rg < 4; ++rg) {
        size_t bt = (size_t)(gt0 + i) * 16 + quad * 4 + rg;
        float val = acc[i][c][rg] + bias;
        if (isf) ((float*)out)[bt * VOCAB + v] = val;
        else     ((u16*)out)[bt * VOCAB + v] = f2bf(val);
      }
    }
  }
}

// ---------- launch ----------

extern "C" void kernel_launch(void* const* d_in, const int* in_sizes, int n_in,
                              void* d_out, int out_size, void* d_ws, size_t ws_size,
                              hipStream_t stream) {
  const int* x            = (const int*)d_in[0];
  const unsigned char* mk = (const unsigned char*)d_in[1];

  char* ws = (char*)d_ws;
  int*   flag  = (int*)(ws + 0);
  float* dbf   = (float*)(ws + 4 * 1024);
  float* gbf   = (float*)(ws + 8 * 1024);            // 24 KB
  int*   flags = (int*)(ws + 32 * 1024);             // 8*32*16*4 = 16 KB
  int*   tokm  = (int*)(ws + 64 * 1024);             // 128 KB
  u16*   dimg  = (u16*)(ws + 192 * 1024);            // 96 KB
  float* P     = (float*)(ws + 288 * 1024);          // 504 KB
  float* P2    = (float*)(ws + 800 * 1024);          // 504 KB
  u64*   exch  = (u64*)(ws + 1312 * 1024);           // 2 MB (8 slots x 256 KB)
  u16*   Wimg  = (u16*)(ws + 3456 * 1024);           // 6 MB
  u16*   Hout  = (u16*)(ws + 10 * 1024 * 1024);      // 64 MB

  detect_kernel<<<1, 256, 0, stream>>>((const u16*)d_in[4], flag);
  conv_kernel<<<(2 * H3 + 255) / 256, 256, 0, stream>>>(d_in[5], gbf, 2 * H3, flag);
  conv_kernel<<<1, 256, 0, stream>>>(d_in[7], dbf, VOCAB, flag);
  tokm_kernel<<<BT / 256, 256, 0, stream>>>(x, mk, tokm);
  proj_kernel<<<VOCAB * (H3 / 256), 256, 0, stream>>>(d_in[2], d_in[3], gbf, P, flag);
  p2_kernel<<<H3, 64, 0, stream>>>(P, gbf, P2);
  pack_wimg_kernel<<<(32 * 32 * 6 * 64 * 8) / 256, 256, 0, stream>>>(d_in[4], Wimg, flag);
  pack_dimg_kernel<<<(32 * 3 * 64 * 8) / 256, 256, 0, stream>>>(d_in[6], dimg, flag);
  hipMemsetAsync(flags, 0, 16 * 1024, stream);
  hipMemsetAsync(exch, 0, SLOT_U64 * 8, stream);     // slot 0 = h_0 = zeros

  gru_persist<<<256, 256, 0, stream>>>((const uint4*)Wimg, tokm, P2, gbf,
                                       exch, Hout, flags);
  dense_mfma<<<256, 256, 0, stream>>>(Hout, (const uint4*)dimg, dbf, d_out, flag);
}